// Round 6
// baseline (156.347 us; speedup 1.0000x reference)
//
#include <hip/hip_runtime.h>
#include <hip/hip_fp16.h>
#include <math.h>

// SpatialSelectiveMRF: s=60000 rows, K=200 components, dz=64, 3 spatial, n=6 neighbors.
// k_point: MFMA (s x 68) @ (68 x 208pad), A=[z|s|1], B=[mu^T|spmu^T|-0.5norm].
// Qc stored TWICE: bf16 rows (own-side, 400B) + e5m2 rows scaled x1024 (gather-side,
// padded to 256B = exactly 4 cache lines).
// ROUND 6: diagnostic A/B — k_point launched 3x (idempotent) to solve for its duration:
//   t_kpoint = (total_r6 - total_r4) / 2
#define KK 200
#define NT 13
#define NNB 6
#define Q8STRIDE 256

typedef __attribute__((ext_vector_type(8))) short short8;
typedef __attribute__((ext_vector_type(4))) float f32x4;
#define MFMA16 __builtin_amdgcn_mfma_f32_16x16x32_bf16

__device__ __forceinline__ unsigned short bfh(float f) {
    unsigned u = __float_as_uint(f);
    return (unsigned short)((u + 0x7fffu + ((u >> 16) & 1u)) >> 16);  // RNE
}
__device__ __forceinline__ float bf2f(unsigned short h) {
    return __uint_as_float(((unsigned)h) << 16);
}
__device__ __forceinline__ short8 z8() {
    short8 v;
#pragma unroll
    for (int j = 0; j < 8; ++j) v[j] = 0;
    return v;
}
__device__ __forceinline__ void cv2(float f, short8& hi, short8& lo, int j) {
    unsigned short h = bfh(f);
    hi[j] = (short)h;
    lo[j] = (short)bfh(f - bf2f(h));
}
// f32 -> e5m2 RNE via fp16 (e5m2 = top byte of fp16, round bit 8)
__device__ __forceinline__ unsigned char f2e5(float f) {
    unsigned short hb = __half_as_ushort(__float2half(f));   // RNE
    return (unsigned char)((hb + 0x7fu + ((hb >> 8) & 1u)) >> 8);
}
// 4 e5m2 bytes of w -> f32 (bits<<8 are valid fp16 patterns)
__device__ __forceinline__ void dec8(unsigned w, float* f) {
    f[0] = __half2float(__ushort_as_half((unsigned short)((w << 8) & 0xff00u)));
    f[1] = __half2float(__ushort_as_half((unsigned short)(w & 0xff00u)));
    f[2] = __half2float(__ushort_as_half((unsigned short)((w >> 8) & 0xff00u)));
    f[3] = __half2float(__ushort_as_half((unsigned short)((w >> 16) & 0xff00u)));
}

// A-frag (16x16x32): lane holds A[m=lane&15][k=(lane>>4)*8 + j].
// B-frag:            lane holds B[k=(lane>>4)*8 + j][n=lane&15].
// C/D:               lane,reg -> D[row=(lane>>4)*4+reg][col=lane&15].
__global__ __launch_bounds__(512, 4) void
k_point(const float* __restrict__ Z, const float* __restrict__ S,
        const float* __restrict__ selmu, const float* __restrict__ spamu,
        unsigned short* __restrict__ Qcb, unsigned char* __restrict__ Qc8,
        float* __restrict__ pointbuf, int sRows, int mTiles)
{
    __shared__ short8 ldsBh[26 * 64];
    __shared__ short8 ldsBl[26 * 64];
    __shared__ uint2  ldsB2h[NT * 16];
    __shared__ uint2  ldsB2l[NT * 16];

    const int tid = threadIdx.x;

    for (int slot = tid; slot < 26 * 64; slot += 512) {
        int L = slot & 63, ts = slot >> 6;
        int t = ts >> 1, sstep = ts & 1;
        int n = t * 16 + (L & 15);
        int kb = sstep * 32 + (L >> 4) * 8;
        short8 hi = z8(), lo = z8();
        if (n < KK) {
            const float* mp = selmu + (size_t)n * 64 + kb;
            float4 a = *(const float4*)mp;
            float4 b = *(const float4*)(mp + 4);
            cv2(a.x, hi, lo, 0); cv2(a.y, hi, lo, 1); cv2(a.z, hi, lo, 2); cv2(a.w, hi, lo, 3);
            cv2(b.x, hi, lo, 4); cv2(b.y, hi, lo, 5); cv2(b.z, hi, lo, 6); cv2(b.w, hi, lo, 7);
        }
        ldsBh[slot] = hi;
        ldsBl[slot] = lo;
    }
    if (tid < NT * 16) {
        int n = tid;
        uint2 vh = make_uint2(0, 0), vl = make_uint2(0, 0);
        if (n < KK) {
            float p0 = spamu[n * 3 + 0], p1 = spamu[n * 3 + 1], p2 = spamu[n * 3 + 2];
            float nrm = p0 * p0 + p1 * p1 + p2 * p2;
            const float* mp = selmu + (size_t)n * 64;
#pragma unroll 8
            for (int k = 0; k < 64; ++k) { float m = mp[k]; nrm = fmaf(m, m, nrm); }
            nrm *= -0.5f;
            unsigned short h0 = bfh(p0), h1 = bfh(p1), h2 = bfh(p2), h3 = bfh(nrm);
            unsigned short g0 = bfh(p0 - bf2f(h0)), g1 = bfh(p1 - bf2f(h1));
            unsigned short g2 = bfh(p2 - bf2f(h2)), g3 = bfh(nrm - bf2f(h3));
            vh = make_uint2((unsigned)h0 | ((unsigned)h1 << 16), (unsigned)h2 | ((unsigned)h3 << 16));
            vl = make_uint2((unsigned)g0 | ((unsigned)g1 << 16), (unsigned)g2 | ((unsigned)g3 << 16));
        }
        ldsB2h[tid] = vh;
        ldsB2l[tid] = vl;
    }
    __syncthreads();

    const int lane = tid & 63;
    const int q = lane >> 4;
    const int li = lane & 15;

    const float cLog = 0.5f * 67.0f * 1.8378770664093453f;

    for (int wg = blockIdx.x * 8 + (tid >> 6); wg < mTiles; wg += gridDim.x * 8) {
        const int m0 = wg * 16;
        const int rowA = (m0 + li < sRows) ? (m0 + li) : (sRows - 1);

        const float* zr = Z + (size_t)rowA * 64 + q * 8;
        float4 z0 = *(const float4*)zr;
        float4 z1 = *(const float4*)(zr + 4);
        float4 z2 = *(const float4*)(zr + 32);
        float4 z3 = *(const float4*)(zr + 36);
        short8 ah0 = z8(), al0 = z8(), ah1 = z8(), al1 = z8();
        cv2(z0.x, ah0, al0, 0); cv2(z0.y, ah0, al0, 1); cv2(z0.z, ah0, al0, 2); cv2(z0.w, ah0, al0, 3);
        cv2(z1.x, ah0, al0, 4); cv2(z1.y, ah0, al0, 5); cv2(z1.z, ah0, al0, 6); cv2(z1.w, ah0, al0, 7);
        cv2(z2.x, ah1, al1, 0); cv2(z2.y, ah1, al1, 1); cv2(z2.z, ah1, al1, 2); cv2(z2.w, ah1, al1, 3);
        cv2(z3.x, ah1, al1, 4); cv2(z3.y, ah1, al1, 5); cv2(z3.z, ah1, al1, 6); cv2(z3.w, ah1, al1, 7);

        float zz = z0.x*z0.x + z0.y*z0.y + z0.z*z0.z + z0.w*z0.w
                 + z1.x*z1.x + z1.y*z1.y + z1.z*z1.z + z1.w*z1.w
                 + z2.x*z2.x + z2.y*z2.y + z2.z*z2.z + z2.w*z2.w
                 + z3.x*z3.x + z3.y*z3.y + z3.z*z3.z + z3.w*z3.w;
        zz += __shfl_xor(zz, 16);
        zz += __shfl_xor(zz, 32);

        float s0v = S[(size_t)rowA * 3 + 0];
        float s1v = S[(size_t)rowA * 3 + 1];
        float s2v = S[(size_t)rowA * 3 + 2];
        float cz = 0.5f * (zz + s0v * s0v + s1v * s1v + s2v * s2v) + cLog;

        short8 a2h = z8(), a2l = z8();
        if (lane < 16) {
            cv2(s0v, a2h, a2l, 0);
            cv2(s1v, a2h, a2l, 1);
            cv2(s2v, a2h, a2l, 2);
            a2h[3] = (short)bfh(1.0f);
        }

        f32x4 acc[NT];
#pragma unroll
        for (int t = 0; t < NT; ++t) { f32x4 zv = {0.f, 0.f, 0.f, 0.f}; acc[t] = zv; }

#pragma unroll
        for (int t = 0; t < NT; ++t) {
            short8 b0 = ldsBh[(t * 2 + 0) * 64 + lane];
            short8 b1 = ldsBh[(t * 2 + 1) * 64 + lane];
            short8 c0 = ldsBl[(t * 2 + 0) * 64 + lane];
            short8 c1 = ldsBl[(t * 2 + 1) * 64 + lane];
            uint2 bh2 = make_uint2(0, 0), bl2 = make_uint2(0, 0);
            if (lane < 16) { bh2 = ldsB2h[t * 16 + lane]; bl2 = ldsB2l[t * 16 + lane]; }
            short8 B2h = z8(), B2l = z8();
            B2h[0] = (short)(bh2.x & 0xffff); B2h[1] = (short)(bh2.x >> 16);
            B2h[2] = (short)(bh2.y & 0xffff); B2h[3] = (short)(bh2.y >> 16);
            B2l[0] = (short)(bl2.x & 0xffff); B2l[1] = (short)(bl2.x >> 16);
            B2l[2] = (short)(bl2.y & 0xffff); B2l[3] = (short)(bl2.y >> 16);

            acc[t] = MFMA16(ah0, b0, acc[t], 0, 0, 0);
            acc[t] = MFMA16(ah1, b1, acc[t], 0, 0, 0);
            acc[t] = MFMA16(al0, b0, acc[t], 0, 0, 0);
            acc[t] = MFMA16(al1, b1, acc[t], 0, 0, 0);
            acc[t] = MFMA16(ah0, c0, acc[t], 0, 0, 0);
            acc[t] = MFMA16(ah1, c1, acc[t], 0, 0, 0);
            acc[t] = MFMA16(a2h, B2h, acc[t], 0, 0, 0);
            acc[t] = MFMA16(a2l, B2h, acc[t], 0, 0, 0);
            acc[t] = MFMA16(a2h, B2l, acc[t], 0, 0, 0);
        }

#pragma unroll
        for (int r = 0; r < 4; ++r) {
            const int row = m0 + q * 4 + r;
            float e[NT];
            float mx = -1e30f;
#pragma unroll
            for (int t = 0; t < NT; ++t) {
                float v = acc[t][r];
                if (t == 12 && li >= 8) v = -1e30f;
                e[t] = v;
                mx = fmaxf(mx, v);
            }
            mx = fmaxf(mx, __shfl_xor(mx, 1));
            mx = fmaxf(mx, __shfl_xor(mx, 2));
            mx = fmaxf(mx, __shfl_xor(mx, 4));
            mx = fmaxf(mx, __shfl_xor(mx, 8));
            float sl = 0.f, pl = 0.f;
#pragma unroll
            for (int t = 0; t < NT; ++t) {
                float v = e[t];
                float ee = __expf(v - mx);
                sl += ee;
                pl = fmaf(ee, v, pl);
                e[t] = ee;
            }
#pragma unroll
            for (int off = 1; off <= 8; off <<= 1) {
                sl += __shfl_xor(sl, off);
                pl += __shfl_xor(pl, off);
            }
            float inv = 1.0f / sl;
            if (row < sRows) {
#pragma unroll
                for (int t = 0; t < NT; ++t) {
                    if (t < 12 || li < 8) {
                        float qv = fminf(fmaxf(e[t] * inv, 1e-6f), 1.0f - 1e-6f);
                        Qcb[(size_t)row * KK + t * 16 + li] = bfh(qv);
                        Qc8[(size_t)row * Q8STRIDE + t * 16 + li] = f2e5(qv * 1024.0f);
                    }
                }
                float czr = __shfl(cz, q * 4 + r);
                if (li == 0) pointbuf[row] = czr - pl * inv;
            }
        }
    }
}

// k_doublet: XCD-matched to k_point; own row bf16, gathers e5m2 x1024 (256B rows).
__global__ __launch_bounds__(512) void
k_doublet(const unsigned short* __restrict__ Qcb, const unsigned char* __restrict__ Qc8,
          const float* __restrict__ pointbuf, const int* __restrict__ D,
          float* __restrict__ out, int sRows, int mTiles)
{
    const int wave = threadIdx.x >> 6;
    const int lane = threadIdx.x & 63;
    const int half = lane >> 5;
    const int l = lane & 31;
    const int sub = blockIdx.x >> 9;
    const int b = blockIdx.x & 511;
    const int T = b * 8 + wave;
    if (T >= mTiles) return;
    const int rbase = T * 16 + sub * 8;

    const bool act = (l < 25);
    const int lc = act ? l : 0;
    const float LN1024 = 6.93147180559945f;

    int   row  = rbase + half;
    int   rowc = (row < sRows) ? row : (sRows - 1);
    uint4 own  = *(const uint4*)(Qcb + (size_t)rowc * KK + lc * 8);
    int   dj[NNB];
    uint2 nb[NNB];
#pragma unroll
    for (int j = 0; j < NNB; ++j) dj[j] = D[(size_t)rowc * NNB + j];
#pragma unroll
    for (int j = 0; j < NNB; ++j) {
        int dd = (dj[j] >= 0) ? dj[j] : rowc;
        nb[j] = *(const uint2*)(Qc8 + (size_t)dd * Q8STRIDE + lc * 8);
    }

    for (int it = 0; it < 4; ++it) {
        int   rowN = 0, rowcN = 0;
        uint4 ownN = make_uint4(0, 0, 0, 0);
        int   djN[NNB];
        uint2 nbN[NNB];
        if (it < 3) {
            rowN  = rbase + (it + 1) * 2 + half;
            rowcN = (rowN < sRows) ? rowN : (sRows - 1);
            ownN  = *(const uint4*)(Qcb + (size_t)rowcN * KK + lc * 8);
#pragma unroll
            for (int j = 0; j < NNB; ++j) djN[j] = D[(size_t)rowcN * NNB + j];
#pragma unroll
            for (int j = 0; j < NNB; ++j) {
                int dd = (djN[j] >= 0) ? djN[j] : rowcN;
                nbN[j] = *(const uint2*)(Qc8 + (size_t)dd * Q8STRIDE + lc * 8);
            }
        }

        float o[8];
        o[0] = bf2f((unsigned short)(own.x & 0xffff)); o[1] = bf2f((unsigned short)(own.x >> 16));
        o[2] = bf2f((unsigned short)(own.y & 0xffff)); o[3] = bf2f((unsigned short)(own.y >> 16));
        o[4] = bf2f((unsigned short)(own.z & 0xffff)); o[5] = bf2f((unsigned short)(own.z >> 16));
        o[6] = bf2f((unsigned short)(own.w & 0xffff)); o[7] = bf2f((unsigned short)(own.w >> 16));

        float pj[NNB];
#pragma unroll
        for (int j = 0; j < NNB; ++j) {
            float bv[8];
            dec8(nb[j].x, bv);
            dec8(nb[j].y, bv + 4);
            float t = o[0] * bv[0];
            t = fmaf(o[1], bv[1], t); t = fmaf(o[2], bv[2], t); t = fmaf(o[3], bv[3], t);
            t = fmaf(o[4], bv[4], t); t = fmaf(o[5], bv[5], t); t = fmaf(o[6], bv[6], t);
            t = fmaf(o[7], bv[7], t);
            pj[j] = act ? t : 0.f;
        }
#pragma unroll
        for (int off = 1; off <= 16; off <<= 1) {
#pragma unroll
            for (int j = 0; j < NNB; ++j) pj[j] += __shfl_xor(pj[j], off);
        }
        float dbl = 0.f;
#pragma unroll
        for (int j = 0; j < NNB; ++j)
            if (dj[j] >= 0) dbl += LN1024 - __logf(pj[j]);   // co = pj / 1024

        if (l == 0 && row < sRows) out[row] = pointbuf[row] + dbl;

        row = rowN; rowc = rowcN; own = ownN;
#pragma unroll
        for (int j = 0; j < NNB; ++j) { dj[j] = djN[j]; nb[j] = nbN[j]; }
    }
}

extern "C" void kernel_launch(void* const* d_in, const int* in_sizes, int n_in,
                              void* d_out, int out_size, void* d_ws, size_t ws_size,
                              hipStream_t stream) {
    const float* Z     = (const float*)d_in[0];
    const float* S     = (const float*)d_in[1];
    const int*   D     = (const int*)d_in[2];
    const float* selmu = (const float*)d_in[3];
    const float* spamu = (const float*)d_in[4];
    float* out = (float*)d_out;
    const int s = out_size;                    // 60000

    const size_t qcbB = (size_t)s * KK * 2;    // bf16 rows
    const size_t qc8B = (size_t)s * Q8STRIDE;  // e5m2 rows, padded
    unsigned short* Qcb = (unsigned short*)d_ws;
    unsigned char*  Qc8 = (unsigned char*)d_ws + qcbB;
    float* pointbuf = (float*)((char*)d_ws + qcbB + qc8B);

    const int mTiles = (s + 15) / 16;          // 3750
    const int grid1 = (mTiles + 7) / 8;        // 469

    // DIAGNOSTIC: 3x idempotent k_point launches -> t_kp = (total - total_r4) / 2
    k_point<<<grid1, 512, 0, stream>>>(Z, S, selmu, spamu, Qcb, Qc8, pointbuf, s, mTiles);
    k_point<<<grid1, 512, 0, stream>>>(Z, S, selmu, spamu, Qcb, Qc8, pointbuf, s, mTiles);
    k_point<<<grid1, 512, 0, stream>>>(Z, S, selmu, spamu, Qcb, Qc8, pointbuf, s, mTiles);

    k_doublet<<<1024, 512, 0, stream>>>(Qcb, Qc8, pointbuf, D, out, s, mTiles);
}

// Round 7
// 108.026 us; speedup vs baseline: 1.4473x; 1.4473x over previous
//
#include <hip/hip_runtime.h>
#include <hip/hip_fp16.h>
#include <math.h>

// SpatialSelectiveMRF: s=60000 rows, K=200 comps, dz=64, 3 spatial, n=6 neighbors.
// R7: TRANSPOSED MFMA k_point — D = Mu(208x68) x [z|s|1]^T(68x16) per tile:
//   lane (q,li) holds comps {mt*16+q*4+r} of row (m0+li)  =>  softmax reduce = 2
//   shuffles (xor16/32), Qc8 store = 1 dword per mt (13 stores/wave vs 104 scalar).
// Qc stored ONCE: e5m2 scaled x1024, 256B rows (4 cache lines).
#define KK 200
#define NT 13
#define NNB 6
#define Q8STRIDE 256

typedef __attribute__((ext_vector_type(8))) short short8;
typedef __attribute__((ext_vector_type(4))) float f32x4;
#define MFMA16 __builtin_amdgcn_mfma_f32_16x16x32_bf16

__device__ __forceinline__ unsigned short bfh(float f) {
    unsigned u = __float_as_uint(f);
    return (unsigned short)((u + 0x7fffu + ((u >> 16) & 1u)) >> 16);  // RNE
}
__device__ __forceinline__ float bf2f(unsigned short h) {
    return __uint_as_float(((unsigned)h) << 16);
}
__device__ __forceinline__ short8 z8() {
    short8 v;
#pragma unroll
    for (int j = 0; j < 8; ++j) v[j] = 0;
    return v;
}
__device__ __forceinline__ void cv2(float f, short8& hi, short8& lo, int j) {
    unsigned short h = bfh(f);
    hi[j] = (short)h;
    lo[j] = (short)bfh(f - bf2f(h));
}
// f32 -> e5m2 RNE via fp16 (e5m2 = top byte of fp16, round bit 8)
__device__ __forceinline__ unsigned f2e5(float f) {
    unsigned short hb = __half_as_ushort(__float2half(f));   // RNE
    return (unsigned)((unsigned short)((hb + 0x7fu + ((hb >> 8) & 1u)) >> 8));
}
// 4 e5m2 bytes -> f32
__device__ __forceinline__ void dec8(unsigned w, float* f) {
    f[0] = __half2float(__ushort_as_half((unsigned short)((w << 8) & 0xff00u)));
    f[1] = __half2float(__ushort_as_half((unsigned short)(w & 0xff00u)));
    f[2] = __half2float(__ushort_as_half((unsigned short)((w >> 8) & 0xff00u)));
    f[3] = __half2float(__ushort_as_half((unsigned short)((w >> 16) & 0xff00u)));
}

// MFMA 16x16x32 layouts: A: lane holds A[m=lane&15][k=(lane>>4)*8+j];
// B: lane holds B[k=(lane>>4)*8+j][n=lane&15]; D: [row=(lane>>4)*4+r][col=lane&15].
// Transposed use: A = comp matrix (m=comp), B = data rows (n=row).
__global__ __launch_bounds__(512, 4) void
k_point(const float* __restrict__ Z, const float* __restrict__ S,
        const float* __restrict__ selmu, const float* __restrict__ spamu,
        unsigned char* __restrict__ Qc8, float* __restrict__ pointbuf,
        int sRows, int mTiles)
{
    __shared__ short8 ldsBh[26 * 64];   // comp-matrix hi frags [mt*2+ks][lane]
    __shared__ short8 ldsBl[26 * 64];   // lo frags
    __shared__ uint2  ldsB2h[NT * 16];  // tail (sp0,sp1,sp2,-0.5norm) hi per comp
    __shared__ uint2  ldsB2l[NT * 16];  // lo

    const int tid = threadIdx.x;

    for (int slot = tid; slot < 26 * 64; slot += 512) {
        int L = slot & 63, ts = slot >> 6;
        int t = ts >> 1, sstep = ts & 1;
        int n = t * 16 + (L & 15);            // comp index
        int kb = sstep * 32 + (L >> 4) * 8;
        short8 hi = z8(), lo = z8();
        if (n < KK) {
            const float* mp = selmu + (size_t)n * 64 + kb;
            float4 a = *(const float4*)mp;
            float4 b = *(const float4*)(mp + 4);
            cv2(a.x, hi, lo, 0); cv2(a.y, hi, lo, 1); cv2(a.z, hi, lo, 2); cv2(a.w, hi, lo, 3);
            cv2(b.x, hi, lo, 4); cv2(b.y, hi, lo, 5); cv2(b.z, hi, lo, 6); cv2(b.w, hi, lo, 7);
        }
        ldsBh[slot] = hi;
        ldsBl[slot] = lo;
    }
    if (tid < NT * 16) {
        int n = tid;
        uint2 vh = make_uint2(0, 0), vl = make_uint2(0, 0);
        if (n < KK) {
            float p0 = spamu[n * 3 + 0], p1 = spamu[n * 3 + 1], p2 = spamu[n * 3 + 2];
            float nrm = p0 * p0 + p1 * p1 + p2 * p2;
            const float* mp = selmu + (size_t)n * 64;
#pragma unroll 8
            for (int k = 0; k < 64; ++k) { float m = mp[k]; nrm = fmaf(m, m, nrm); }
            nrm *= -0.5f;
            unsigned short h0 = bfh(p0), h1 = bfh(p1), h2 = bfh(p2), h3 = bfh(nrm);
            unsigned short g0 = bfh(p0 - bf2f(h0)), g1 = bfh(p1 - bf2f(h1));
            unsigned short g2 = bfh(p2 - bf2f(h2)), g3 = bfh(nrm - bf2f(h3));
            vh = make_uint2((unsigned)h0 | ((unsigned)h1 << 16), (unsigned)h2 | ((unsigned)h3 << 16));
            vl = make_uint2((unsigned)g0 | ((unsigned)g1 << 16), (unsigned)g2 | ((unsigned)g3 << 16));
        }
        ldsB2h[tid] = vh;
        ldsB2l[tid] = vl;
    }
    __syncthreads();   // no barriers after this point

    const int wave = tid >> 6;
    const int lane = tid & 63;
    const int q = lane >> 4;
    const int li = lane & 15;
    const float cLog = 0.5f * 67.0f * 1.8378770664093453f;

    const int tile = blockIdx.x * 8 + wave;
    if (tile >= mTiles) return;
    const int m0 = tile * 16;
    const int row = m0 + li;                         // this lane's row (exact: s%16==0)
    const int rowA = (row < sRows) ? row : (sRows - 1);

    // ---- row-side B frags: z hi/lo (B[k][n=row li], lane's k = q*8+j) ----
    const float* zr = Z + (size_t)rowA * 64 + q * 8;
    float4 z0 = *(const float4*)zr;
    float4 z1 = *(const float4*)(zr + 4);
    float4 z2 = *(const float4*)(zr + 32);
    float4 z3 = *(const float4*)(zr + 36);
    short8 ah0 = z8(), al0 = z8(), ah1 = z8(), al1 = z8();
    cv2(z0.x, ah0, al0, 0); cv2(z0.y, ah0, al0, 1); cv2(z0.z, ah0, al0, 2); cv2(z0.w, ah0, al0, 3);
    cv2(z1.x, ah0, al0, 4); cv2(z1.y, ah0, al0, 5); cv2(z1.z, ah0, al0, 6); cv2(z1.w, ah0, al0, 7);
    cv2(z2.x, ah1, al1, 0); cv2(z2.y, ah1, al1, 1); cv2(z2.z, ah1, al1, 2); cv2(z2.w, ah1, al1, 3);
    cv2(z3.x, ah1, al1, 4); cv2(z3.y, ah1, al1, 5); cv2(z3.z, ah1, al1, 6); cv2(z3.w, ah1, al1, 7);

    float zz = z0.x*z0.x + z0.y*z0.y + z0.z*z0.z + z0.w*z0.w
             + z1.x*z1.x + z1.y*z1.y + z1.z*z1.z + z1.w*z1.w
             + z2.x*z2.x + z2.y*z2.y + z2.z*z2.z + z2.w*z2.w
             + z3.x*z3.x + z3.y*z3.y + z3.z*z3.z + z3.w*z3.w;
    zz += __shfl_xor(zz, 16);
    zz += __shfl_xor(zz, 32);

    float s0v = S[(size_t)rowA * 3 + 0];
    float s1v = S[(size_t)rowA * 3 + 1];
    float s2v = S[(size_t)rowA * 3 + 2];
    float cz = 0.5f * (zz + s0v * s0v + s1v * s1v + s2v * s2v) + cLog;

    // tail row frag: lanes q==0 hold {s0,s1,s2,1} (k_local 0..3) of row li
    short8 rsh = z8(), rsl = z8();
    if (lane < 16) {
        cv2(s0v, rsh, rsl, 0);
        cv2(s1v, rsh, rsl, 1);
        cv2(s2v, rsh, rsl, 2);
        rsh[3] = (short)bfh(1.0f);
    }

    f32x4 acc[NT];
#pragma unroll
    for (int t = 0; t < NT; ++t) { f32x4 zv = {0.f, 0.f, 0.f, 0.f}; acc[t] = zv; }

#pragma unroll
    for (int t = 0; t < NT; ++t) {
        short8 b0 = ldsBh[(t * 2 + 0) * 64 + lane];
        short8 b1 = ldsBh[(t * 2 + 1) * 64 + lane];
        short8 c0 = ldsBl[(t * 2 + 0) * 64 + lane];
        short8 c1 = ldsBl[(t * 2 + 1) * 64 + lane];
        uint2 bh2 = make_uint2(0, 0), bl2 = make_uint2(0, 0);
        if (lane < 16) { bh2 = ldsB2h[t * 16 + lane]; bl2 = ldsB2l[t * 16 + lane]; }
        short8 cmh = z8(), cml = z8();
        cmh[0] = (short)(bh2.x & 0xffff); cmh[1] = (short)(bh2.x >> 16);
        cmh[2] = (short)(bh2.y & 0xffff); cmh[3] = (short)(bh2.y >> 16);
        cml[0] = (short)(bl2.x & 0xffff); cml[1] = (short)(bl2.x >> 16);
        cml[2] = (short)(bl2.y & 0xffff); cml[3] = (short)(bl2.y >> 16);

        // D[comp][row]: A = comp matrix, B = data row  (operands swapped vs r4)
        acc[t] = MFMA16(b0, ah0, acc[t], 0, 0, 0);   // mu_h x z_h
        acc[t] = MFMA16(b1, ah1, acc[t], 0, 0, 0);
        acc[t] = MFMA16(b0, al0, acc[t], 0, 0, 0);   // mu_h x z_l
        acc[t] = MFMA16(b1, al1, acc[t], 0, 0, 0);
        acc[t] = MFMA16(c0, ah0, acc[t], 0, 0, 0);   // mu_l x z_h
        acc[t] = MFMA16(c1, ah1, acc[t], 0, 0, 0);
        acc[t] = MFMA16(cmh, rsh, acc[t], 0, 0, 0);  // tail hi x hi
        acc[t] = MFMA16(cmh, rsl, acc[t], 0, 0, 0);  // tail hi x lo
        acc[t] = MFMA16(cml, rsh, acc[t], 0, 0, 0);  // tail lo x hi
    }

    // ---- epilogue: lane (q,li) holds comps {mt*16+q*4+r} of row li ----
    const bool padQ = (q >= 2);                 // comps 200..207 live at mt==12,q>=2
    float mx = -1e30f;
#pragma unroll
    for (int t = 0; t < NT; ++t) {
#pragma unroll
        for (int r = 0; r < 4; ++r) {
            float v = acc[t][r];
            if (t == 12 && padQ) v = -1e30f;
            acc[t][r] = v;
            mx = fmaxf(mx, v);
        }
    }
    mx = fmaxf(mx, __shfl_xor(mx, 16));
    mx = fmaxf(mx, __shfl_xor(mx, 32));
    float sl = 0.f, pl = 0.f;
#pragma unroll
    for (int t = 0; t < NT; ++t) {
#pragma unroll
        for (int r = 0; r < 4; ++r) {
            float v = acc[t][r];
            float ee = __expf(v - mx);          // pad -> 0
            sl += ee;
            pl = fmaf(ee, v, pl);
            acc[t][r] = ee;
        }
    }
    sl += __shfl_xor(sl, 16);
    sl += __shfl_xor(sl, 32);
    pl += __shfl_xor(pl, 16);
    pl += __shfl_xor(pl, 32);
    float inv = 1.0f / sl;

    if (row < sRows) {
        unsigned char* qp = Qc8 + (size_t)row * Q8STRIDE + q * 4;
#pragma unroll
        for (int t = 0; t < NT; ++t) {
            unsigned w = 0;
            if (t < 12 || !padQ) {
                float q0 = fminf(fmaxf(acc[t][0] * inv, 1e-6f), 1.0f - 1e-6f);
                float q1 = fminf(fmaxf(acc[t][1] * inv, 1e-6f), 1.0f - 1e-6f);
                float q2 = fminf(fmaxf(acc[t][2] * inv, 1e-6f), 1.0f - 1e-6f);
                float q3 = fminf(fmaxf(acc[t][3] * inv, 1e-6f), 1.0f - 1e-6f);
                w = f2e5(q0 * 1024.0f) | (f2e5(q1 * 1024.0f) << 8)
                  | (f2e5(q2 * 1024.0f) << 16) | (f2e5(q3 * 1024.0f) << 24);
            }
            *(unsigned*)(qp + t * 16) = w;      // 1 dword store per mt
        }
        if (lane < 16) pointbuf[row] = cz - pl * inv;
    }
}

// k_doublet: own + gathers all from Qc8 (e5m2 x1024). 2 rows/wave (32-lane halves),
// 4 iters. 3-stage pipeline: D[it+2] | gathers[it+1] | consume[it].
__global__ __launch_bounds__(512) void
k_doublet(const unsigned char* __restrict__ Qc8, const float* __restrict__ pointbuf,
          const int* __restrict__ D, float* __restrict__ out, int sRows, int mTiles)
{
    const int wave = threadIdx.x >> 6;
    const int lane = threadIdx.x & 63;
    const int half = lane >> 5;
    const int l = lane & 31;
    const int sub = blockIdx.x >> 9;
    const int b = blockIdx.x & 511;
    const int T = b * 8 + wave;                 // XCD-matched to k_point writer block b
    if (T >= mTiles) return;
    const int rbase = T * 16 + sub * 8 + half;  // rows rbase, rbase+2, +4, +6

    const bool act = (l < 25);
    const int lc = act ? l : 0;
    const float LN2_20 = 13.862943611198906f;   // own,nb both x1024 -> co x 2^20

    int   dj0[NNB], dj1[NNB], dj2[NNB];
    uint2 nb0[NNB], nb1[NNB];
    uint2 ow0, ow1;
    {
        int rc0 = rbase,     c0 = (rc0 < sRows) ? rc0 : (sRows - 1);
        int rc1 = rbase + 2, c1 = (rc1 < sRows) ? rc1 : (sRows - 1);
#pragma unroll
        for (int j = 0; j < NNB; ++j) dj0[j] = D[(size_t)c0 * NNB + j];
#pragma unroll
        for (int j = 0; j < NNB; ++j) dj1[j] = D[(size_t)c1 * NNB + j];
        ow0 = *(const uint2*)(Qc8 + (size_t)c0 * Q8STRIDE + lc * 8);
        ow1 = *(const uint2*)(Qc8 + (size_t)c1 * Q8STRIDE + lc * 8);
#pragma unroll
        for (int j = 0; j < NNB; ++j) {
            int dd = (dj0[j] >= 0) ? dj0[j] : c0;
            nb0[j] = *(const uint2*)(Qc8 + (size_t)dd * Q8STRIDE + lc * 8);
        }
    }

    for (int it = 0; it < 4; ++it) {
        const int row = rbase + it * 2;
        // D for it+2 (off critical path of it+1's gathers)
        if (it < 2) {
            int rc = rbase + (it + 2) * 2;
            int cc = (rc < sRows) ? rc : (sRows - 1);
#pragma unroll
            for (int j = 0; j < NNB; ++j) dj2[j] = D[(size_t)cc * NNB + j];
        }
        // gathers for it+1 (dj1 loaded one full iteration ago)
        if (it < 3) {
            int rc = rbase + (it + 1) * 2;
            int cc = (rc < sRows) ? rc : (sRows - 1);
#pragma unroll
            for (int j = 0; j < NNB; ++j) {
                int dd = (dj1[j] >= 0) ? dj1[j] : cc;
                nb1[j] = *(const uint2*)(Qc8 + (size_t)dd * Q8STRIDE + lc * 8);
            }
        }

        // consume it
        float o[8];
        dec8(ow0.x, o);
        dec8(ow0.y, o + 4);
        float pj[NNB];
#pragma unroll
        for (int j = 0; j < NNB; ++j) {
            float bv[8];
            dec8(nb0[j].x, bv);
            dec8(nb0[j].y, bv + 4);
            float t = o[0] * bv[0];
            t = fmaf(o[1], bv[1], t); t = fmaf(o[2], bv[2], t); t = fmaf(o[3], bv[3], t);
            t = fmaf(o[4], bv[4], t); t = fmaf(o[5], bv[5], t); t = fmaf(o[6], bv[6], t);
            t = fmaf(o[7], bv[7], t);
            pj[j] = act ? t : 0.f;
        }
#pragma unroll
        for (int off = 1; off <= 16; off <<= 1) {
#pragma unroll
            for (int j = 0; j < NNB; ++j) pj[j] += __shfl_xor(pj[j], off);
        }
        float dbl = 0.f;
#pragma unroll
        for (int j = 0; j < NNB; ++j)
            if (dj0[j] >= 0) dbl += LN2_20 - __logf(pj[j]);

        if (l == 0 && row < sRows) out[row] = pointbuf[row] + dbl;

        // rotate pipeline; own-row prefetch one ahead (sequential, cheap)
        ow0 = ow1;
        if (it < 2) {
            int rc = rbase + (it + 2) * 2;
            int cc = (rc < sRows) ? rc : (sRows - 1);
            ow1 = *(const uint2*)(Qc8 + (size_t)cc * Q8STRIDE + lc * 8);
        }
#pragma unroll
        for (int j = 0; j < NNB; ++j) { dj0[j] = dj1[j]; dj1[j] = dj2[j]; nb0[j] = nb1[j]; }
    }
}

extern "C" void kernel_launch(void* const* d_in, const int* in_sizes, int n_in,
                              void* d_out, int out_size, void* d_ws, size_t ws_size,
                              hipStream_t stream) {
    const float* Z     = (const float*)d_in[0];
    const float* S     = (const float*)d_in[1];
    const int*   D     = (const int*)d_in[2];
    const float* selmu = (const float*)d_in[3];
    const float* spamu = (const float*)d_in[4];
    float* out = (float*)d_out;
    const int s = out_size;                    // 60000

    unsigned char* Qc8 = (unsigned char*)d_ws;                   // s*256 B = 15.36 MB
    float* pointbuf = (float*)((char*)d_ws + (size_t)s * Q8STRIDE);

    const int mTiles = (s + 15) / 16;          // 3750
    const int grid1 = (mTiles + 7) / 8;        // 469
    k_point<<<grid1, 512, 0, stream>>>(Z, S, selmu, spamu, Qc8, pointbuf, s, mTiles);

    k_doublet<<<1024, 512, 0, stream>>>(Qc8, pointbuf, D, out, s, mTiles);
}

// Round 8
// 107.489 us; speedup vs baseline: 1.4545x; 1.0050x over previous
//
#include <hip/hip_runtime.h>
#include <hip/hip_fp16.h>
#include <math.h>

// SpatialSelectiveMRF: s=60000 rows, K=200 comps, dz=64, 3 spatial, n=6 neighbors.
// k_point (unchanged from R7): transposed MFMA, D = Mu(208x68) x [z|s|1]^T(68x16).
// k_doublet (R8): ONE ROW PER WAVE — all gathers issue in a single round
// (3 neighbor-pairs across 32-lane halves), max TLP (60000 waves), scalar D loads.
#define KK 200
#define NT 13
#define NNB 6
#define Q8STRIDE 256

typedef __attribute__((ext_vector_type(8))) short short8;
typedef __attribute__((ext_vector_type(4))) float f32x4;
#define MFMA16 __builtin_amdgcn_mfma_f32_16x16x32_bf16

__device__ __forceinline__ unsigned short bfh(float f) {
    unsigned u = __float_as_uint(f);
    return (unsigned short)((u + 0x7fffu + ((u >> 16) & 1u)) >> 16);  // RNE
}
__device__ __forceinline__ float bf2f(unsigned short h) {
    return __uint_as_float(((unsigned)h) << 16);
}
__device__ __forceinline__ short8 z8() {
    short8 v;
#pragma unroll
    for (int j = 0; j < 8; ++j) v[j] = 0;
    return v;
}
__device__ __forceinline__ void cv2(float f, short8& hi, short8& lo, int j) {
    unsigned short h = bfh(f);
    hi[j] = (short)h;
    lo[j] = (short)bfh(f - bf2f(h));
}
// f32 -> e5m2 RNE via fp16 (e5m2 = top byte of fp16, round bit 8)
__device__ __forceinline__ unsigned f2e5(float f) {
    unsigned short hb = __half_as_ushort(__float2half(f));   // RNE
    return (unsigned)((unsigned short)((hb + 0x7fu + ((hb >> 8) & 1u)) >> 8));
}
// 4 e5m2 bytes -> f32
__device__ __forceinline__ void dec8(unsigned w, float* f) {
    f[0] = __half2float(__ushort_as_half((unsigned short)((w << 8) & 0xff00u)));
    f[1] = __half2float(__ushort_as_half((unsigned short)(w & 0xff00u)));
    f[2] = __half2float(__ushort_as_half((unsigned short)((w >> 8) & 0xff00u)));
    f[3] = __half2float(__ushort_as_half((unsigned short)((w >> 16) & 0xff00u)));
}

// MFMA 16x16x32 layouts: A: lane holds A[m=lane&15][k=(lane>>4)*8+j];
// B: lane holds B[k=(lane>>4)*8+j][n=lane&15]; D: [row=(lane>>4)*4+r][col=lane&15].
__global__ __launch_bounds__(512, 4) void
k_point(const float* __restrict__ Z, const float* __restrict__ S,
        const float* __restrict__ selmu, const float* __restrict__ spamu,
        unsigned char* __restrict__ Qc8, float* __restrict__ pointbuf,
        int sRows, int mTiles)
{
    __shared__ short8 ldsBh[26 * 64];
    __shared__ short8 ldsBl[26 * 64];
    __shared__ uint2  ldsB2h[NT * 16];
    __shared__ uint2  ldsB2l[NT * 16];

    const int tid = threadIdx.x;

    for (int slot = tid; slot < 26 * 64; slot += 512) {
        int L = slot & 63, ts = slot >> 6;
        int t = ts >> 1, sstep = ts & 1;
        int n = t * 16 + (L & 15);
        int kb = sstep * 32 + (L >> 4) * 8;
        short8 hi = z8(), lo = z8();
        if (n < KK) {
            const float* mp = selmu + (size_t)n * 64 + kb;
            float4 a = *(const float4*)mp;
            float4 b = *(const float4*)(mp + 4);
            cv2(a.x, hi, lo, 0); cv2(a.y, hi, lo, 1); cv2(a.z, hi, lo, 2); cv2(a.w, hi, lo, 3);
            cv2(b.x, hi, lo, 4); cv2(b.y, hi, lo, 5); cv2(b.z, hi, lo, 6); cv2(b.w, hi, lo, 7);
        }
        ldsBh[slot] = hi;
        ldsBl[slot] = lo;
    }
    if (tid < NT * 16) {
        int n = tid;
        uint2 vh = make_uint2(0, 0), vl = make_uint2(0, 0);
        if (n < KK) {
            float p0 = spamu[n * 3 + 0], p1 = spamu[n * 3 + 1], p2 = spamu[n * 3 + 2];
            float nrm = p0 * p0 + p1 * p1 + p2 * p2;
            const float* mp = selmu + (size_t)n * 64;
#pragma unroll 8
            for (int k = 0; k < 64; ++k) { float m = mp[k]; nrm = fmaf(m, m, nrm); }
            nrm *= -0.5f;
            unsigned short h0 = bfh(p0), h1 = bfh(p1), h2 = bfh(p2), h3 = bfh(nrm);
            unsigned short g0 = bfh(p0 - bf2f(h0)), g1 = bfh(p1 - bf2f(h1));
            unsigned short g2 = bfh(p2 - bf2f(h2)), g3 = bfh(nrm - bf2f(h3));
            vh = make_uint2((unsigned)h0 | ((unsigned)h1 << 16), (unsigned)h2 | ((unsigned)h3 << 16));
            vl = make_uint2((unsigned)g0 | ((unsigned)g1 << 16), (unsigned)g2 | ((unsigned)g3 << 16));
        }
        ldsB2h[tid] = vh;
        ldsB2l[tid] = vl;
    }
    __syncthreads();

    const int wave = tid >> 6;
    const int lane = tid & 63;
    const int q = lane >> 4;
    const int li = lane & 15;
    const float cLog = 0.5f * 67.0f * 1.8378770664093453f;

    const int tile = blockIdx.x * 8 + wave;
    if (tile >= mTiles) return;
    const int m0 = tile * 16;
    const int row = m0 + li;
    const int rowA = (row < sRows) ? row : (sRows - 1);

    const float* zr = Z + (size_t)rowA * 64 + q * 8;
    float4 z0 = *(const float4*)zr;
    float4 z1 = *(const float4*)(zr + 4);
    float4 z2 = *(const float4*)(zr + 32);
    float4 z3 = *(const float4*)(zr + 36);
    short8 ah0 = z8(), al0 = z8(), ah1 = z8(), al1 = z8();
    cv2(z0.x, ah0, al0, 0); cv2(z0.y, ah0, al0, 1); cv2(z0.z, ah0, al0, 2); cv2(z0.w, ah0, al0, 3);
    cv2(z1.x, ah0, al0, 4); cv2(z1.y, ah0, al0, 5); cv2(z1.z, ah0, al0, 6); cv2(z1.w, ah0, al0, 7);
    cv2(z2.x, ah1, al1, 0); cv2(z2.y, ah1, al1, 1); cv2(z2.z, ah1, al1, 2); cv2(z2.w, ah1, al1, 3);
    cv2(z3.x, ah1, al1, 4); cv2(z3.y, ah1, al1, 5); cv2(z3.z, ah1, al1, 6); cv2(z3.w, ah1, al1, 7);

    float zz = z0.x*z0.x + z0.y*z0.y + z0.z*z0.z + z0.w*z0.w
             + z1.x*z1.x + z1.y*z1.y + z1.z*z1.z + z1.w*z1.w
             + z2.x*z2.x + z2.y*z2.y + z2.z*z2.z + z2.w*z2.w
             + z3.x*z3.x + z3.y*z3.y + z3.z*z3.z + z3.w*z3.w;
    zz += __shfl_xor(zz, 16);
    zz += __shfl_xor(zz, 32);

    float s0v = S[(size_t)rowA * 3 + 0];
    float s1v = S[(size_t)rowA * 3 + 1];
    float s2v = S[(size_t)rowA * 3 + 2];
    float cz = 0.5f * (zz + s0v * s0v + s1v * s1v + s2v * s2v) + cLog;

    short8 rsh = z8(), rsl = z8();
    if (lane < 16) {
        cv2(s0v, rsh, rsl, 0);
        cv2(s1v, rsh, rsl, 1);
        cv2(s2v, rsh, rsl, 2);
        rsh[3] = (short)bfh(1.0f);
    }

    f32x4 acc[NT];
#pragma unroll
    for (int t = 0; t < NT; ++t) { f32x4 zv = {0.f, 0.f, 0.f, 0.f}; acc[t] = zv; }

#pragma unroll
    for (int t = 0; t < NT; ++t) {
        short8 b0 = ldsBh[(t * 2 + 0) * 64 + lane];
        short8 b1 = ldsBh[(t * 2 + 1) * 64 + lane];
        short8 c0 = ldsBl[(t * 2 + 0) * 64 + lane];
        short8 c1 = ldsBl[(t * 2 + 1) * 64 + lane];
        uint2 bh2 = make_uint2(0, 0), bl2 = make_uint2(0, 0);
        if (lane < 16) { bh2 = ldsB2h[t * 16 + lane]; bl2 = ldsB2l[t * 16 + lane]; }
        short8 cmh = z8(), cml = z8();
        cmh[0] = (short)(bh2.x & 0xffff); cmh[1] = (short)(bh2.x >> 16);
        cmh[2] = (short)(bh2.y & 0xffff); cmh[3] = (short)(bh2.y >> 16);
        cml[0] = (short)(bl2.x & 0xffff); cml[1] = (short)(bl2.x >> 16);
        cml[2] = (short)(bl2.y & 0xffff); cml[3] = (short)(bl2.y >> 16);

        acc[t] = MFMA16(b0, ah0, acc[t], 0, 0, 0);
        acc[t] = MFMA16(b1, ah1, acc[t], 0, 0, 0);
        acc[t] = MFMA16(b0, al0, acc[t], 0, 0, 0);
        acc[t] = MFMA16(b1, al1, acc[t], 0, 0, 0);
        acc[t] = MFMA16(c0, ah0, acc[t], 0, 0, 0);
        acc[t] = MFMA16(c1, ah1, acc[t], 0, 0, 0);
        acc[t] = MFMA16(cmh, rsh, acc[t], 0, 0, 0);
        acc[t] = MFMA16(cmh, rsl, acc[t], 0, 0, 0);
        acc[t] = MFMA16(cml, rsh, acc[t], 0, 0, 0);
    }

    const bool padQ = (q >= 2);
    float mx = -1e30f;
#pragma unroll
    for (int t = 0; t < NT; ++t) {
#pragma unroll
        for (int r = 0; r < 4; ++r) {
            float v = acc[t][r];
            if (t == 12 && padQ) v = -1e30f;
            acc[t][r] = v;
            mx = fmaxf(mx, v);
        }
    }
    mx = fmaxf(mx, __shfl_xor(mx, 16));
    mx = fmaxf(mx, __shfl_xor(mx, 32));
    float sl = 0.f, pl = 0.f;
#pragma unroll
    for (int t = 0; t < NT; ++t) {
#pragma unroll
        for (int r = 0; r < 4; ++r) {
            float v = acc[t][r];
            float ee = __expf(v - mx);
            sl += ee;
            pl = fmaf(ee, v, pl);
            acc[t][r] = ee;
        }
    }
    sl += __shfl_xor(sl, 16);
    sl += __shfl_xor(sl, 32);
    pl += __shfl_xor(pl, 16);
    pl += __shfl_xor(pl, 32);
    float inv = 1.0f / sl;

    if (row < sRows) {
        unsigned char* qp = Qc8 + (size_t)row * Q8STRIDE + q * 4;
#pragma unroll
        for (int t = 0; t < NT; ++t) {
            unsigned w = 0;
            if (t < 12 || !padQ) {
                float q0 = fminf(fmaxf(acc[t][0] * inv, 1e-6f), 1.0f - 1e-6f);
                float q1 = fminf(fmaxf(acc[t][1] * inv, 1e-6f), 1.0f - 1e-6f);
                float q2 = fminf(fmaxf(acc[t][2] * inv, 1e-6f), 1.0f - 1e-6f);
                float q3 = fminf(fmaxf(acc[t][3] * inv, 1e-6f), 1.0f - 1e-6f);
                w = f2e5(q0 * 1024.0f) | (f2e5(q1 * 1024.0f) << 8)
                  | (f2e5(q2 * 1024.0f) << 16) | (f2e5(q3 * 1024.0f) << 24);
            }
            *(unsigned*)(qp + t * 16) = w;
        }
        if (lane < 16) pointbuf[row] = cz - pl * inv;
    }
}

// k_doublet R8: one row per wave. Halves take alternating neighbors (j = 2i+half),
// so own + all 6 gathers issue in ONE round (no serial gather chain). 60000 waves,
// tiny VGPR footprint -> 32 waves/CU of latency-hiding TLP.
__global__ __launch_bounds__(512, 8) void
k_doublet(const unsigned char* __restrict__ Qc8, const float* __restrict__ pointbuf,
          const int* __restrict__ D, float* __restrict__ out, int sRows)
{
    const int wave = threadIdx.x >> 6;
    const int lane = threadIdx.x & 63;
    const int half = lane >> 5;
    const int l = lane & 31;
    const int row = blockIdx.x * 8 + wave;
    if (row >= sRows) return;

    const bool act = (l < 25);
    const int lc = act ? l : 0;
    const float LN2_20 = 13.862943611198906f;   // own,nb both x1024 -> co x 2^20

    // D row: wave-uniform addresses -> scalar loads; select per-half via cndmask
    const int* dp = D + (size_t)row * NNB;
    int da0 = dp[0], da1 = dp[1], da2 = dp[2], da3 = dp[3], da4 = dp[4], da5 = dp[5];
    int dj[3];
    dj[0] = half ? da1 : da0;
    dj[1] = half ? da3 : da2;
    dj[2] = half ? da5 : da4;

    // all 4 memory rounds issue back-to-back (independent)
    uint2 ow = *(const uint2*)(Qc8 + (size_t)row * Q8STRIDE + lc * 8);
    uint2 nb[3];
#pragma unroll
    for (int i = 0; i < 3; ++i) {
        int dd = (dj[i] >= 0) ? dj[i] : row;
        nb[i] = *(const uint2*)(Qc8 + (size_t)dd * Q8STRIDE + lc * 8);
    }

    float o[8];
    dec8(ow.x, o);
    dec8(ow.y, o + 4);

    float pj[3];
#pragma unroll
    for (int i = 0; i < 3; ++i) {
        float bv[8];
        dec8(nb[i].x, bv);
        dec8(nb[i].y, bv + 4);
        float t = o[0] * bv[0];
        t = fmaf(o[1], bv[1], t); t = fmaf(o[2], bv[2], t); t = fmaf(o[3], bv[3], t);
        t = fmaf(o[4], bv[4], t); t = fmaf(o[5], bv[5], t); t = fmaf(o[6], bv[6], t);
        t = fmaf(o[7], bv[7], t);
        pj[i] = act ? t : 0.f;
    }
    // butterfly within each 32-half: reduces all 3 neighbor-dots of both halves
#pragma unroll
    for (int off = 1; off <= 16; off <<= 1) {
#pragma unroll
        for (int i = 0; i < 3; ++i) pj[i] += __shfl_xor(pj[i], off);
    }
    float dbl = 0.f;
#pragma unroll
    for (int i = 0; i < 3; ++i)
        if (dj[i] >= 0) dbl += LN2_20 - __logf(pj[i]);
    dbl += __shfl_xor(dbl, 32);   // combine the two halves' neighbor triples

    if (lane == 0) out[row] = pointbuf[row] + dbl;
}

extern "C" void kernel_launch(void* const* d_in, const int* in_sizes, int n_in,
                              void* d_out, int out_size, void* d_ws, size_t ws_size,
                              hipStream_t stream) {
    const float* Z     = (const float*)d_in[0];
    const float* S     = (const float*)d_in[1];
    const int*   D     = (const int*)d_in[2];
    const float* selmu = (const float*)d_in[3];
    const float* spamu = (const float*)d_in[4];
    float* out = (float*)d_out;
    const int s = out_size;                    // 60000

    unsigned char* Qc8 = (unsigned char*)d_ws;                   // s*256 B = 15.36 MB
    float* pointbuf = (float*)((char*)d_ws + (size_t)s * Q8STRIDE);

    const int mTiles = (s + 15) / 16;          // 3750
    const int grid1 = (mTiles + 7) / 8;        // 469
    k_point<<<grid1, 512, 0, stream>>>(Z, S, selmu, spamu, Qc8, pointbuf, s, mTiles);

    const int grid2 = (s + 7) / 8;             // 7500: one row per wave
    k_doublet<<<grid2, 512, 0, stream>>>(Qc8, pointbuf, D, out, s);
}